// Round 4
// baseline (419.825 us; speedup 1.0000x reference)
//
#include <hip/hip_runtime.h>
#include <hip/hip_fp16.h>

#define B_ 8
#define C_ 16
#define H_ 240
#define W_ 320
#define N_ (H_*W_)

__device__ __forceinline__ void twist2mat_dev(float w0, float w1, float w2, float R[9]) {
    float th = sqrtf(w0*w0 + w1*w1 + w2*w2) + 1e-12f;
    float ax = w0/th, ay = w1/th, az = w2/th;
    float s = sinf(th), c = cosf(th), ic = 1.0f - c;
    R[0] = 1.0f + ic*(ax*ax - 1.0f);
    R[1] = -s*az + ic*ax*ay;
    R[2] =  s*ay + ic*ax*az;
    R[3] =  s*az + ic*ax*ay;
    R[4] = 1.0f + ic*(ay*ay - 1.0f);
    R[5] = -s*ax + ic*ay*az;
    R[6] = -s*ay + ic*ax*az;
    R[7] =  s*ax + ic*ay*az;
    R[8] = 1.0f + ic*(az*az - 1.0f);
}

__device__ __forceinline__ unsigned pack_h2(float a, float b) {
    __half2 h = __floats2half2_rn(a, b);
    return *reinterpret_cast<unsigned*>(&h);
}
__device__ __forceinline__ float2 unpack_h2(unsigned u) {
    __half2 h = *reinterpret_cast<__half2*>(&u);
    return __half22float2(h);
}

// One damped-GN solve step from accumulated [21 upper-tri JtWJ | 6 rhs]; updates R,t.
__device__ __forceinline__ void solve_update(const float* __restrict__ ac, float R[9], float t[3]) {
    float M[6][7];
    {
        int idx = 0;
        #pragma unroll
        for (int k = 0; k < 6; k++)
            #pragma unroll
            for (int l = k; l < 6; l++) { M[k][l] = ac[idx]; M[l][k] = ac[idx]; idx++; }
    }
    const float trace = M[0][0]+M[1][1]+M[2][2]+M[3][3]+M[4][4]+M[5][5];
    const float lam = trace * 1e-6f;
    #pragma unroll
    for (int i = 0; i < 6; i++) { M[i][i] += lam; M[i][6] = ac[21+i]; }

    #pragma unroll
    for (int k = 0; k < 6; k++) {
        const float inv = 1.0f / M[k][k];
        #pragma unroll
        for (int i = k+1; i < 6; i++) {
            const float f = M[i][k] * inv;
            #pragma unroll
            for (int j = k; j < 7; j++) M[i][j] -= f * M[k][j];
        }
    }
    float xi[6];
    #pragma unroll
    for (int i = 5; i >= 0; i--) {
        float s = M[i][6];
        #pragma unroll
        for (int j = i+1; j < 6; j++) s -= M[i][j]*xi[j];
        xi[i] = s / M[i][i];
    }

    float dR[9];
    twist2mat_dev(-xi[0], -xi[1], -xi[2], dR);
    const float dt0 = -(dR[0]*xi[3] + dR[1]*xi[4] + dR[2]*xi[5]);
    const float dt1 = -(dR[3]*xi[3] + dR[4]*xi[4] + dR[5]*xi[5]);
    const float dt2 = -(dR[6]*xi[3] + dR[7]*xi[4] + dR[8]*xi[5]);

    const float nt0 = R[0]*dt0 + R[1]*dt1 + R[2]*dt2 + t[0];
    const float nt1 = R[3]*dt0 + R[4]*dt1 + R[5]*dt2 + t[1];
    const float nt2 = R[6]*dt0 + R[7]*dt1 + R[8]*dt2 + t[2];
    float nR[9];
    #pragma unroll
    for (int i = 0; i < 3; i++)
        #pragma unroll
        for (int j = 0; j < 3; j++)
            nR[i*3+j] = R[i*3+0]*dR[0*3+j] + R[i*3+1]*dR[1*3+j] + R[i*3+2]*dR[2*3+j];
    #pragma unroll
    for (int i = 0; i < 9; i++) R[i] = nR[i];
    t[0] = nt0; t[1] = nt1; t[2] = nt2;
}

__device__ __forceinline__ void build_RT(const float* __restrict__ twist0,
                                         const float* __restrict__ accum,
                                         int b, int iters, float R[9], float t[3]) {
    const float* w = twist0 + b*6;
    twist2mat_dev(w[0], w[1], w[2], R);
    t[0] = w[3]; t[1] = w[4]; t[2] = w[5];
    for (int j = 0; j < iters; j++)
        solve_update(accum + (size_t)(j*B_ + b)*27, R, t);
}

// Iteration-invariant precompute, 1 pixel x 4 channels per thread.
// x0 sobel neighborhood staged through LDS via cooperative float4 loads.
//  P0h  : [b][cp=0..7][pix] uint4 = {h2(gx,gy), h2(x0,s0^2)} x 2 channels (16 B)
//  X1S1h: [b][cg=0..3][pix] uint4 = h2(x1,s1) x 4 channels (16 B, gather target)
// Block (0,0,0) also zeroes the 3 per-iteration accumulator sets.
__launch_bounds__(256)
__global__ void precompute_kernel(const float* __restrict__ x0, const float* __restrict__ x1,
                                  const float* __restrict__ sigma0, const float* __restrict__ sigma1,
                                  uint4* __restrict__ P0h, uint4* __restrict__ X1S1h,
                                  float* __restrict__ accum)
{
    if (blockIdx.x == 0 && blockIdx.y == 0 && blockIdx.z == 0) {
        for (int k = threadIdx.x; k < 3*B_*27; k += 256) accum[k] = 0.0f;
    }
    const int b  = blockIdx.z;
    const int cg = blockIdx.y;
    const int base_pix = blockIdx.x * 256;
    const int pix = base_pix + threadIdx.x;
    const int h0 = base_pix / W_;          // first row touched by this block

    __shared__ float lds[4][4][W_];        // [ch][row][col] = 20 KB

    const size_t cbase = ((size_t)(b*C_) + cg*4) * N_;

    // aux loads issued early (overlap with LDS fill); coalesced dword loads
    float s0a[4], x1a[4], s1a[4];
    #pragma unroll
    for (int i = 0; i < 4; i++) {
        const size_t o = cbase + (size_t)i*N_ + pix;
        s0a[i] = sigma0[o];
        x1a[i] = x1[o];
        s1a[i] = sigma1[o];
    }

    // cooperative x0 tile: 4 ch x 4 rows (h0-1..h0+2, clamped) x 320 cols
    // = 1280 float4 loads for the block -> 5 per thread, fully coalesced.
    #pragma unroll
    for (int k = 0; k < 5; k++) {
        const int idx = threadIdx.x + k*256;          // 0..1279
        const int ch  = idx / 320;
        const int rem = idx - ch*320;
        const int row = rem / 80;
        const int c4  = rem - row*80;
        const int src_r = min(max(h0 - 1 + row, 0), H_ - 1);
        const float4 v = *reinterpret_cast<const float4*>(
            x0 + cbase + (size_t)ch*N_ + (size_t)src_r*W_ + c4*4);
        *reinterpret_cast<float4*>(&lds[ch][row][c4*4]) = v;
    }
    __syncthreads();

    const int h = pix / W_;
    const int w = pix - h*W_;
    const int lr = h - (h0 - 1);                      // 1 or 2
    const int wm = max(w-1, 0), wp = min(w+1, W_-1);

    unsigned gq[4], xq[4], qq[4];
    #pragma unroll
    for (int i = 0; i < 4; i++) {
        const float* rT = lds[i][lr-1];
        const float* rM = lds[i][lr];
        const float* rB = lds[i][lr+1];
        const float tl = rT[wm], tc_ = rT[w], tr = rT[wp];
        const float ml = rM[wm], ctr = rM[w], mr = rM[wp];
        const float bl = rB[wm], bc_ = rB[w], br = rB[wp];
        const float dx = tr - tl + 2.0f*(mr - ml) + (br - bl);
        const float dy = bl - tl + 2.0f*(bc_ - tc_) + (br - tr);
        const float mag = sqrtf(dx*dx + dy*dy + 1e-8f);
        gq[i] = pack_h2(dx/mag, dy/mag);
        xq[i] = pack_h2(ctr, s0a[i]*s0a[i]);
        qq[i] = pack_h2(x1a[i], s1a[i]);
    }

    uint4 A;  A.x = gq[0];  A.y = xq[0];  A.z = gq[1];  A.w = xq[1];
    uint4 Bw; Bw.x = gq[2]; Bw.y = xq[2]; Bw.z = gq[3]; Bw.w = xq[3];
    uint4 Q;  Q.x = qq[0];  Q.y = qq[1];  Q.z = qq[2];  Q.w = qq[3];
    P0h[((size_t)(b*8 + cg*2  ))*N_ + pix] = A;
    P0h[((size_t)(b*8 + cg*2+1))*N_ + pix] = Bw;
    X1S1h[((size_t)(b*4 + cg))*N_ + pix] = Q;
}

struct Warp {
    int i00, i01, i10, i11;
    float w00, w01, w10, w11;
    float inv_z;
    float px, py;
    bool  inview;
};

__device__ __forceinline__ Warp make_warp(int pix, float d, const float Rm[9], const float tv[3],
                                          float fx, float fy, float cx, float cy) {
    Warp W;
    const int h = pix / W_;
    const int w = pix - h*W_;
    W.px = ((float)w - cx) / fx;
    W.py = ((float)h - cy) / fy;
    const float x_ = Rm[0]*W.px + Rm[1]*W.py + Rm[2] + tv[0]*d;
    const float y_ = Rm[3]*W.px + Rm[4]*W.py + Rm[5] + tv[1]*d;
    const float s_ = Rm[6]*W.px + Rm[7]*W.py + Rm[8] + tv[2]*d;
    const float u = x_/s_*fx + cx;
    const float v = y_/s_*fy + cy;
    W.inv_z = d / s_;
    const float uc = fminf(fmaxf(u, 0.0f), (float)(W_-1));
    const float vc = fminf(fmaxf(v, 0.0f), (float)(H_-1));
    const float x0f = floorf(uc), y0f = floorf(vc);
    const float wx = uc - x0f, wy = vc - y0f;
    const int x0i = (int)x0f, y0i = (int)y0f;
    const int x1i = min(x0i+1, W_-1), y1i = min(y0i+1, H_-1);
    W.w00 = (1.0f-wx)*(1.0f-wy); W.w01 = wx*(1.0f-wy);
    W.w10 = (1.0f-wx)*wy;        W.w11 = wx*wy;
    W.i00 = y0i*W_+x0i; W.i01 = y0i*W_+x1i; W.i10 = y1i*W_+x0i; W.i11 = y1i*W_+x1i;
    W.inview = (u > 0.0f) && (u < (float)W_) && (v > 0.0f) && (v < (float)H_);
    return W;
}

// 5-sum channel accumulate: S = {Swxx, Swxy, Swyy, Srx, Sry}
__device__ __forceinline__ void ch_accum(const Warp& W, float S[5],
                                         unsigned gword, unsigned xword,
                                         unsigned t00, unsigned t01, unsigned t10, unsigned t11) {
    const float2 g  = unpack_h2(gword);
    const float2 xs = unpack_h2(xword);
    const float2 a00 = unpack_h2(t00), a01 = unpack_h2(t01),
                 a10 = unpack_h2(t10), a11 = unpack_h2(t11);
    const float fr = a00.x*W.w00 + a01.x*W.w01 + a10.x*W.w10 + a11.x*W.w11;
    const float sr = a00.y*W.w00 + a01.y*W.w01 + a10.y*W.w10 + a11.y*W.w11;
    const float inv_s2 = 1.0f/(sr*sr + xs.y);
    const float res = fr - xs.x;
    const float gxw = g.x*inv_s2, gyw = g.y*inv_s2;
    S[0] += g.x*gxw; S[1] += g.x*gyw; S[2] += g.y*gyw;
    S[3] += res*gxw; S[4] += res*gyw;
}

// Branch-free, dual-pixel iter kernel: both pixels' gathers issued per cg batch
// (2x memory-level parallelism, no control-flow barrier to load hoisting).
// Occlusion/in-view handled by multiplying the 5 channel-sums by {0,1}.
__launch_bounds__(256)
__global__ void iter_kernel(const uint4* __restrict__ P0h, const uint4* __restrict__ X1S1h,
                            const float* __restrict__ invD0, const float* __restrict__ invD1,
                            const float* __restrict__ Kmat, const float* __restrict__ twist0,
                            float* __restrict__ accum, int it)
{
    const int b = blockIdx.y;
    const int pixA = blockIdx.x * 512 + threadIdx.x;
    const int pixB = pixA + 256;

    float Rm[9], tv[3];
    build_RT(twist0, accum, b, it, Rm, tv);

    const float fx = Kmat[b*4+0], fy = Kmat[b*4+1], cx = Kmat[b*4+2], cy = Kmat[b*4+3];

    const float* d0 = invD0 + b*N_;
    const float* dz = invD1 + b*N_;
    const uint4* P0b   = P0h   + (size_t)b*8*N_;
    const uint4* X1S1b = X1S1h + (size_t)b*4*N_;

    const float dA = d0[pixA];
    const float dB = d0[pixB];

    const Warp A = make_warp(pixA, dA, Rm, tv, fx, fy, cx, cy);
    const Warp B = make_warp(pixB, dB, Rm, tv, fx, fy, cx, cy);

    // occlusion check: both pixels' dz gathers in flight together
    const float zA00 = dz[A.i00], zA01 = dz[A.i01], zA10 = dz[A.i10], zA11 = dz[A.i11];
    const float zB00 = dz[B.i00], zB01 = dz[B.i01], zB10 = dz[B.i10], zB11 = dz[B.i11];
    const float zwA = zA00*A.w00 + zA01*A.w01 + zA10*A.w10 + zA11*A.w11;
    const float zwB = zB00*B.w00 + zB01*B.w01 + zB10*B.w10 + zB11*B.w11;
    const float vmA = (A.inv_z > zwA - 0.1f && A.inview) ? 1.0f : 0.0f;
    const float vmB = (B.inv_z > zwB - 0.1f && B.inview) ? 1.0f : 0.0f;

    float SA[5] = {0.f,0.f,0.f,0.f,0.f};
    float SB[5] = {0.f,0.f,0.f,0.f,0.f};

    #pragma unroll
    for (int cg = 0; cg < 4; cg++) {
        const uint4 pAa = P0b[(size_t)(cg*2  )*N_ + pixA];
        const uint4 pAb = P0b[(size_t)(cg*2+1)*N_ + pixA];
        const uint4 pBa = P0b[(size_t)(cg*2  )*N_ + pixB];
        const uint4 pBb = P0b[(size_t)(cg*2+1)*N_ + pixB];
        const uint4* xsb = X1S1b + (size_t)cg*N_;
        const uint4 qA00 = xsb[A.i00], qA01 = xsb[A.i01], qA10 = xsb[A.i10], qA11 = xsb[A.i11];
        const uint4 qB00 = xsb[B.i00], qB01 = xsb[B.i01], qB10 = xsb[B.i10], qB11 = xsb[B.i11];

        ch_accum(A, SA, pAa.x, pAa.y, qA00.x, qA01.x, qA10.x, qA11.x);
        ch_accum(A, SA, pAa.z, pAa.w, qA00.y, qA01.y, qA10.y, qA11.y);
        ch_accum(A, SA, pAb.x, pAb.y, qA00.z, qA01.z, qA10.z, qA11.z);
        ch_accum(A, SA, pAb.z, pAb.w, qA00.w, qA01.w, qA10.w, qA11.w);

        ch_accum(B, SB, pBa.x, pBa.y, qB00.x, qB01.x, qB10.x, qB11.x);
        ch_accum(B, SB, pBa.z, pBa.w, qB00.y, qB01.y, qB10.y, qB11.y);
        ch_accum(B, SB, pBb.x, pBb.y, qB00.z, qB01.z, qB10.z, qB11.z);
        ch_accum(B, SB, pBb.z, pBb.w, qB00.w, qB01.w, qB10.w, qB11.w);
    }

    #pragma unroll
    for (int k = 0; k < 5; k++) { SA[k] *= vmA; SB[k] *= vmB; }

    // Jacobian row vectors (recomputed after the channel loop to cap live registers)
    float AvA[6], BvA[6], AvB[6], BvB[6];
    {
        const float xyA = A.px*A.py;
        AvA[0] = -xyA*fx; AvA[1] = (1.0f+A.px*A.px)*fx; AvA[2] = -A.py*fx;
        AvA[3] = dA*fx;   AvA[4] = 0.0f;                AvA[5] = -dA*A.px*fx;
        BvA[0] = -(1.0f+A.py*A.py)*fy; BvA[1] = xyA*fy; BvA[2] = A.px*fy;
        BvA[3] = 0.0f;    BvA[4] = dA*fy;               BvA[5] = -dA*A.py*fy;
        const float xyB = B.px*B.py;
        AvB[0] = -xyB*fx; AvB[1] = (1.0f+B.px*B.px)*fx; AvB[2] = -B.py*fx;
        AvB[3] = dB*fx;   AvB[4] = 0.0f;                AvB[5] = -dB*B.px*fx;
        BvB[0] = -(1.0f+B.py*B.py)*fy; BvB[1] = xyB*fy; BvB[2] = B.px*fy;
        BvB[3] = 0.0f;    BvB[4] = dB*fy;               BvB[5] = -dB*B.py*fy;
    }

    float acc[27];
    {
        int idx = 0;
        #pragma unroll
        for (int k = 0; k < 6; k++) {
            #pragma unroll
            for (int l = k; l < 6; l++) {
                acc[idx++] =
                    SA[0]*AvA[k]*AvA[l] + SA[1]*(AvA[k]*BvA[l] + BvA[k]*AvA[l]) + SA[2]*BvA[k]*BvA[l] +
                    SB[0]*AvB[k]*AvB[l] + SB[1]*(AvB[k]*BvB[l] + BvB[k]*AvB[l]) + SB[2]*BvB[k]*BvB[l];
            }
        }
        #pragma unroll
        for (int k = 0; k < 6; k++)
            acc[21+k] = SA[3]*AvA[k] + SA[4]*BvA[k] + SB[3]*AvB[k] + SB[4]*BvB[k];
    }

    const int lane = threadIdx.x & 63;
    const int wave = threadIdx.x >> 6;
    __shared__ float red[4][27];
    #pragma unroll
    for (int j = 0; j < 27; j++) {
        float vv = acc[j];
        vv += __shfl_down(vv, 32);
        vv += __shfl_down(vv, 16);
        vv += __shfl_down(vv, 8);
        vv += __shfl_down(vv, 4);
        vv += __shfl_down(vv, 2);
        vv += __shfl_down(vv, 1);
        if (lane == 0) red[wave][j] = vv;
    }
    __syncthreads();
    if (threadIdx.x < 27) {
        float s = red[0][threadIdx.x] + red[1][threadIdx.x] + red[2][threadIdx.x] + red[3][threadIdx.x];
        atomicAdd(&accum[(size_t)(it*B_ + b)*27 + threadIdx.x], s);
    }
}

__global__ void finalize_kernel(const float* __restrict__ twist0, const float* __restrict__ accum,
                                float* __restrict__ out)
{
    const int b = threadIdx.x;
    if (b >= B_) return;
    float Rm[9], tv[3];
    build_RT(twist0, accum, b, 3, Rm, tv);
    float* ob = out + b*12;
    #pragma unroll
    for (int i = 0; i < 9; i++) ob[i] = Rm[i];
    ob[9] = tv[0]; ob[10] = tv[1]; ob[11] = tv[2];
}

extern "C" void kernel_launch(void* const* d_in, const int* in_sizes, int n_in,
                              void* d_out, int out_size, void* d_ws, size_t ws_size,
                              hipStream_t stream) {
    const float* twist0 = (const float*)d_in[0];
    const float* x0     = (const float*)d_in[1];
    const float* x1     = (const float*)d_in[2];
    const float* invD0  = (const float*)d_in[3];
    const float* invD1  = (const float*)d_in[4];
    const float* sigma0 = (const float*)d_in[5];
    const float* sigma1 = (const float*)d_in[6];
    const float* Kmat   = (const float*)d_in[7];
    float* out = (float*)d_out;

    const size_t p0_bytes = (size_t)B_*8*N_*sizeof(uint4);   // 78.6 MB
    const size_t xs_bytes = (size_t)B_*4*N_*sizeof(uint4);   // 39.3 MB

    uint4* P0h   = (uint4*)d_ws;
    uint4* X1S1h = (uint4*)((char*)d_ws + p0_bytes);
    float* accum = (float*)((char*)d_ws + p0_bytes + xs_bytes);  // 3*B_*27 floats

    hipLaunchKernelGGL(precompute_kernel, dim3(N_/256, 4, B_), dim3(256), 0, stream,
                       x0, x1, sigma0, sigma1, P0h, X1S1h, accum);

    dim3 grid(N_/512, B_);
    for (int it = 0; it < 3; ++it) {
        hipLaunchKernelGGL(iter_kernel, grid, dim3(256), 0, stream,
                           P0h, X1S1h, invD0, invD1, Kmat, twist0, accum, it);
    }
    hipLaunchKernelGGL(finalize_kernel, dim3(1), dim3(64), 0, stream, twist0, accum, out);
}

// Round 6
// 357.796 us; speedup vs baseline: 1.1734x; 1.1734x over previous
//
#include <hip/hip_runtime.h>
#include <hip/hip_fp16.h>

#define B_ 8
#define C_ 16
#define H_ 240
#define W_ 320
#define N_ (H_*W_)
#define ITER_BLOCKS ((N_/512)*B_)   // 1200

__device__ __forceinline__ void twist2mat_dev(float w0, float w1, float w2, float R[9]) {
    float th = sqrtf(w0*w0 + w1*w1 + w2*w2) + 1e-12f;
    float ax = w0/th, ay = w1/th, az = w2/th;
    float s = sinf(th), c = cosf(th), ic = 1.0f - c;
    R[0] = 1.0f + ic*(ax*ax - 1.0f);
    R[1] = -s*az + ic*ax*ay;
    R[2] =  s*ay + ic*ax*az;
    R[3] =  s*az + ic*ax*ay;
    R[4] = 1.0f + ic*(ay*ay - 1.0f);
    R[5] = -s*ax + ic*ay*az;
    R[6] = -s*ay + ic*ax*az;
    R[7] =  s*ax + ic*ay*az;
    R[8] = 1.0f + ic*(az*az - 1.0f);
}

__device__ __forceinline__ unsigned pack_h2(float a, float b) {
    __half2 h = __floats2half2_rn(a, b);
    return *reinterpret_cast<unsigned*>(&h);
}
__device__ __forceinline__ float2 unpack_h2(unsigned u) {
    __half2 h = *reinterpret_cast<__half2*>(&u);
    return __half22float2(h);
}

// One damped-GN solve step from accumulated [21 upper-tri JtWJ | 6 rhs]; updates R,t.
__device__ __forceinline__ void solve_update(const float* __restrict__ ac, float R[9], float t[3]) {
    float M[6][7];
    {
        int idx = 0;
        #pragma unroll
        for (int k = 0; k < 6; k++)
            #pragma unroll
            for (int l = k; l < 6; l++) { M[k][l] = ac[idx]; M[l][k] = ac[idx]; idx++; }
    }
    const float trace = M[0][0]+M[1][1]+M[2][2]+M[3][3]+M[4][4]+M[5][5];
    const float lam = trace * 1e-6f;
    #pragma unroll
    for (int i = 0; i < 6; i++) { M[i][i] += lam; M[i][6] = ac[21+i]; }

    #pragma unroll
    for (int k = 0; k < 6; k++) {
        const float inv = 1.0f / M[k][k];
        #pragma unroll
        for (int i = k+1; i < 6; i++) {
            const float f = M[i][k] * inv;
            #pragma unroll
            for (int j = k; j < 7; j++) M[i][j] -= f * M[k][j];
        }
    }
    float xi[6];
    #pragma unroll
    for (int i = 5; i >= 0; i--) {
        float s = M[i][6];
        #pragma unroll
        for (int j = i+1; j < 6; j++) s -= M[i][j]*xi[j];
        xi[i] = s / M[i][i];
    }

    float dR[9];
    twist2mat_dev(-xi[0], -xi[1], -xi[2], dR);
    const float dt0 = -(dR[0]*xi[3] + dR[1]*xi[4] + dR[2]*xi[5]);
    const float dt1 = -(dR[3]*xi[3] + dR[4]*xi[4] + dR[5]*xi[5]);
    const float dt2 = -(dR[6]*xi[3] + dR[7]*xi[4] + dR[8]*xi[5]);

    const float nt0 = R[0]*dt0 + R[1]*dt1 + R[2]*dt2 + t[0];
    const float nt1 = R[3]*dt0 + R[4]*dt1 + R[5]*dt2 + t[1];
    const float nt2 = R[6]*dt0 + R[7]*dt1 + R[8]*dt2 + t[2];
    float nR[9];
    #pragma unroll
    for (int i = 0; i < 3; i++)
        #pragma unroll
        for (int j = 0; j < 3; j++)
            nR[i*3+j] = R[i*3+0]*dR[0*3+j] + R[i*3+1]*dR[1*3+j] + R[i*3+2]*dR[2*3+j];
    #pragma unroll
    for (int i = 0; i < 9; i++) R[i] = nR[i];
    t[0] = nt0; t[1] = nt1; t[2] = nt2;
}

__device__ __forceinline__ void build_RT(const float* __restrict__ twist0,
                                         const float* __restrict__ accum,
                                         int b, int iters, float R[9], float t[3]) {
    const float* w = twist0 + b*6;
    twist2mat_dev(w[0], w[1], w[2], R);
    t[0] = w[3]; t[1] = w[4]; t[2] = w[5];
    for (int j = 0; j < iters; j++)
        solve_update(accum + (size_t)(j*B_ + b)*27, R, t);
}

// Iteration-invariant precompute, 1 pixel x 4 channels per thread.
// ALL global reads are cooperative float4 through LDS: x0 sobel tile (20 KB)
// plus x1/sigma0/sigma1 aux (12 KB). VMEM instr/thread: 20 -> 11
// (precompute measured VMEM-issue-bound at ~1 instr/cyc/CU).
//  P0h  : [b][cp=0..7][pix] uint4 = {h2(gx,gy), h2(x0,s0^2)} x 2 channels (16 B)
//  X1S1h: [b][cg=0..3][pix] uint4 = h2(x1,s1) x 4 channels (16 B, gather target)
// Block (0,0,0) also zeroes the 3 per-iteration accumulator sets + done-counter.
__launch_bounds__(256)
__global__ void precompute_kernel(const float* __restrict__ x0, const float* __restrict__ x1,
                                  const float* __restrict__ sigma0, const float* __restrict__ sigma1,
                                  uint4* __restrict__ P0h, uint4* __restrict__ X1S1h,
                                  float* __restrict__ accum, unsigned* __restrict__ counter)
{
    if (blockIdx.x == 0 && blockIdx.y == 0 && blockIdx.z == 0) {
        for (int k = threadIdx.x; k < 3*B_*27; k += 256) accum[k] = 0.0f;
        if (threadIdx.x == 0) *counter = 0u;
    }
    const int b  = blockIdx.z;
    const int cg = blockIdx.y;
    const int base_pix = blockIdx.x * 256;
    const int pix = base_pix + threadIdx.x;
    const int h0 = base_pix / W_;          // first row touched by this block

    __shared__ float lds[4][4][W_];        // x0 [ch][row][col], 20 KB
    __shared__ float auxl[3][4][256];      // {x1,s0,s1}[ch][px], 12 KB

    const size_t cbase = ((size_t)(b*C_) + cg*4) * N_;

    // cooperative x0 tile: 4 ch x 4 rows (h0-1..h0+2, clamped) x 320 cols
    // = 1280 float4 loads for the block -> 5 per thread, fully coalesced.
    #pragma unroll
    for (int k = 0; k < 5; k++) {
        const int idx = threadIdx.x + k*256;          // 0..1279
        const int ch  = idx / 320;
        const int rem = idx - ch*320;
        const int row = rem / 80;
        const int c4  = rem - row*80;
        const int src_r = min(max(h0 - 1 + row, 0), H_ - 1);
        const float4 v = *reinterpret_cast<const float4*>(
            x0 + cbase + (size_t)ch*N_ + (size_t)src_r*W_ + c4*4);
        *reinterpret_cast<float4*>(&lds[ch][row][c4*4]) = v;
    }
    // cooperative aux: per array, wave w loads channel w's 256 px as 64 float4
    {
        const int ch = threadIdx.x >> 6;              // 0..3 (one wave per channel)
        const int c4 = threadIdx.x & 63;              // 0..63
        const size_t off = cbase + (size_t)ch*N_ + base_pix + c4*4;
        const float4 v0 = *reinterpret_cast<const float4*>(x1     + off);
        const float4 v1 = *reinterpret_cast<const float4*>(sigma0 + off);
        const float4 v2 = *reinterpret_cast<const float4*>(sigma1 + off);
        *reinterpret_cast<float4*>(&auxl[0][ch][c4*4]) = v0;
        *reinterpret_cast<float4*>(&auxl[1][ch][c4*4]) = v1;
        *reinterpret_cast<float4*>(&auxl[2][ch][c4*4]) = v2;
    }
    __syncthreads();

    const int h = pix / W_;
    const int w = pix - h*W_;
    const int lr = h - (h0 - 1);                      // 1 or 2
    const int wm = max(w-1, 0), wp = min(w+1, W_-1);

    unsigned gq[4], xq[4], qq[4];
    #pragma unroll
    for (int i = 0; i < 4; i++) {
        const float* rT = lds[i][lr-1];
        const float* rM = lds[i][lr];
        const float* rB = lds[i][lr+1];
        const float tl = rT[wm], tc_ = rT[w], tr = rT[wp];
        const float ml = rM[wm], ctr = rM[w], mr = rM[wp];
        const float bl = rB[wm], bc_ = rB[w], br = rB[wp];
        const float dx = tr - tl + 2.0f*(mr - ml) + (br - bl);
        const float dy = bl - tl + 2.0f*(bc_ - tc_) + (br - tr);
        const float mag = sqrtf(dx*dx + dy*dy + 1e-8f);
        const float s0v = auxl[1][i][threadIdx.x];
        gq[i] = pack_h2(dx/mag, dy/mag);
        xq[i] = pack_h2(ctr, s0v*s0v);
        qq[i] = pack_h2(auxl[0][i][threadIdx.x], auxl[2][i][threadIdx.x]);
    }

    uint4 A;  A.x = gq[0];  A.y = xq[0];  A.z = gq[1];  A.w = xq[1];
    uint4 Bw; Bw.x = gq[2]; Bw.y = xq[2]; Bw.z = gq[3]; Bw.w = xq[3];
    uint4 Q;  Q.x = qq[0];  Q.y = qq[1];  Q.z = qq[2];  Q.w = qq[3];
    P0h[((size_t)(b*8 + cg*2  ))*N_ + pix] = A;
    P0h[((size_t)(b*8 + cg*2+1))*N_ + pix] = Bw;
    X1S1h[((size_t)(b*4 + cg))*N_ + pix] = Q;
}

// Per-pixel residual/weight accumulation into the shared 27-value accumulator.
// (Round-2 verified body, unchanged.)
__device__ __forceinline__ void accum_pixel(int pix,
                                            const float Rm[9], const float tv[3],
                                            float fx, float fy, float cx, float cy,
                                            const uint4* __restrict__ P0b,
                                            const uint4* __restrict__ X1S1b,
                                            const float* __restrict__ d0,
                                            const float* __restrict__ dz,
                                            float* __restrict__ acc)
{
    const int h = pix / W_;
    const int w = pix - h*W_;

    const float px = ((float)w - cx) / fx;
    const float py = ((float)h - cy) / fy;
    const float d  = d0[pix];

    const float x_ = Rm[0]*px + Rm[1]*py + Rm[2] + tv[0]*d;
    const float y_ = Rm[3]*px + Rm[4]*py + Rm[5] + tv[1]*d;
    const float s_ = Rm[6]*px + Rm[7]*py + Rm[8] + tv[2]*d;
    const float u = x_/s_*fx + cx;
    const float v = y_/s_*fy + cy;
    const float inv_z = d / s_;

    const float uc = fminf(fmaxf(u, 0.0f), (float)(W_-1));
    const float vc = fminf(fmaxf(v, 0.0f), (float)(H_-1));
    const float x0f = floorf(uc), y0f = floorf(vc);
    const float wx = uc - x0f, wy = vc - y0f;
    const int x0i = (int)x0f, y0i = (int)y0f;
    const int x1i = min(x0i+1, W_-1), y1i = min(y0i+1, H_-1);
    const float w00 = (1.0f-wx)*(1.0f-wy), w01 = wx*(1.0f-wy);
    const float w10 = (1.0f-wx)*wy,        w11 = wx*wy;
    const int i00 = y0i*W_+x0i, i01 = y0i*W_+x1i, i10 = y1i*W_+x0i, i11 = y1i*W_+x1i;

    const float zw = dz[i00]*w00 + dz[i01]*w01 + dz[i10]*w10 + dz[i11]*w11;
    const bool inlier = inv_z > zw - 0.1f;
    const bool inview = (u > 0.0f) && (u < (float)W_) && (v > 0.0f) && (v < (float)H_);
    const bool valid  = inlier && inview;

    if (!valid) return;

    const float xy = px*py;
    const float Av[6] = { -xy*fx, (1.0f+px*px)*fx, -py*fx, d*fx, 0.0f, -d*px*fx };
    const float Bv[6] = { -(1.0f+py*py)*fy, xy*fy, px*fy, 0.0f, d*fy, -d*py*fy };

    float Swxx=0.f, Swxy=0.f, Swyy=0.f, Srx=0.f, Sry=0.f;

#define CH(gword, xword, t00, t01, t10, t11) { \
    const float2 g  = unpack_h2(gword); \
    const float2 xs = unpack_h2(xword); \
    const float2 a00 = unpack_h2(t00), a01 = unpack_h2(t01), \
                 a10 = unpack_h2(t10), a11 = unpack_h2(t11); \
    const float fr = a00.x*w00 + a01.x*w01 + a10.x*w10 + a11.x*w11; \
    const float sr = a00.y*w00 + a01.y*w01 + a10.y*w10 + a11.y*w11; \
    const float inv_s2 = 1.0f/(sr*sr + xs.y); \
    const float res = fr - xs.x; \
    const float gxw = g.x*inv_s2, gyw = g.y*inv_s2; \
    Swxx += g.x*gxw; Swxy += g.x*gyw; Swyy += g.y*gyw; \
    Srx  += res*gxw; Sry  += res*gyw; }

    #pragma unroll
    for (int cgi = 0; cgi < 4; cgi++) {
        const uint4 pA = P0b[(size_t)(cgi*2  )*N_ + pix];
        const uint4 pB = P0b[(size_t)(cgi*2+1)*N_ + pix];
        const uint4* xsb = X1S1b + (size_t)cgi*N_;
        const uint4 q00 = xsb[i00], q01 = xsb[i01], q10 = xsb[i10], q11 = xsb[i11];
        CH(pA.x, pA.y, q00.x, q01.x, q10.x, q11.x)
        CH(pA.z, pA.w, q00.y, q01.y, q10.y, q11.y)
        CH(pB.x, pB.y, q00.z, q01.z, q10.z, q11.z)
        CH(pB.z, pB.w, q00.w, q01.w, q10.w, q11.w)
    }
#undef CH

    int idx = 0;
    #pragma unroll
    for (int k = 0; k < 6; k++) {
        #pragma unroll
        for (int l = k; l < 6; l++) {
            acc[idx++] += Swxx*Av[k]*Av[l] + Swxy*(Av[k]*Bv[l] + Bv[k]*Av[l]) + Swyy*Bv[k]*Bv[l];
        }
    }
    #pragma unroll
    for (int k = 0; k < 6; k++) acc[21+k] += Srx*Av[k] + Sry*Bv[k];
}

// 2 pixels per thread (R2 verified structure). On the last iteration the
// final block (device-scope done-counter) also performs the finalize,
// removing a separate launch.
__launch_bounds__(256)
__global__ void iter_kernel(const uint4* __restrict__ P0h, const uint4* __restrict__ X1S1h,
                            const float* __restrict__ invD0, const float* __restrict__ invD1,
                            const float* __restrict__ Kmat, const float* __restrict__ twist0,
                            float* __restrict__ accum, unsigned* __restrict__ counter,
                            float* __restrict__ out, int it, int do_final)
{
    const int b = blockIdx.y;
    const int pix0 = blockIdx.x * 512 + threadIdx.x;

    float Rm[9], tv[3];
    build_RT(twist0, accum, b, it, Rm, tv);

    const float fx = Kmat[b*4+0], fy = Kmat[b*4+1], cx = Kmat[b*4+2], cy = Kmat[b*4+3];

    float acc[27];
    #pragma unroll
    for (int j = 0; j < 27; j++) acc[j] = 0.0f;

    const uint4* P0b   = P0h   + (size_t)b*8*N_;
    const uint4* X1S1b = X1S1h + (size_t)b*4*N_;
    const float* d0 = invD0 + b*N_;
    const float* dz = invD1 + b*N_;

    accum_pixel(pix0,       Rm, tv, fx, fy, cx, cy, P0b, X1S1b, d0, dz, acc);
    accum_pixel(pix0 + 256, Rm, tv, fx, fy, cx, cy, P0b, X1S1b, d0, dz, acc);

    const int lane = threadIdx.x & 63;
    const int wave = threadIdx.x >> 6;
    __shared__ float red[4][27];
    #pragma unroll
    for (int j = 0; j < 27; j++) {
        float vv = acc[j];
        vv += __shfl_down(vv, 32);
        vv += __shfl_down(vv, 16);
        vv += __shfl_down(vv, 8);
        vv += __shfl_down(vv, 4);
        vv += __shfl_down(vv, 2);
        vv += __shfl_down(vv, 1);
        if (lane == 0) red[wave][j] = vv;
    }
    __syncthreads();
    if (threadIdx.x < 27) {
        float s = red[0][threadIdx.x] + red[1][threadIdx.x] + red[2][threadIdx.x] + red[3][threadIdx.x];
        atomicAdd(&accum[(size_t)(it*B_ + b)*27 + threadIdx.x], s);
    }

    if (do_final) {
        __shared__ int amlast;
        __syncthreads();                     // this block's atomicAdds executed
        if (threadIdx.x == 0) {
            __threadfence();                 // adds globally visible before counter bump
            amlast = (atomicAdd(counter, 1u) == (unsigned)(ITER_BLOCKS - 1)) ? 1 : 0;
        }
        __syncthreads();
        if (amlast && threadIdx.x < B_) {    // all blocks' adds precede last counter bump
            const int fb = threadIdx.x;
            float fR[9], ft[3];
            build_RT(twist0, accum, fb, 3, fR, ft);
            float* ob = out + fb*12;
            #pragma unroll
            for (int i = 0; i < 9; i++) ob[i] = fR[i];
            ob[9] = ft[0]; ob[10] = ft[1]; ob[11] = ft[2];
        }
    }
}

extern "C" void kernel_launch(void* const* d_in, const int* in_sizes, int n_in,
                              void* d_out, int out_size, void* d_ws, size_t ws_size,
                              hipStream_t stream) {
    const float* twist0 = (const float*)d_in[0];
    const float* x0     = (const float*)d_in[1];
    const float* x1     = (const float*)d_in[2];
    const float* invD0  = (const float*)d_in[3];
    const float* invD1  = (const float*)d_in[4];
    const float* sigma0 = (const float*)d_in[5];
    const float* sigma1 = (const float*)d_in[6];
    const float* Kmat   = (const float*)d_in[7];
    float* out = (float*)d_out;

    const size_t p0_bytes = (size_t)B_*8*N_*sizeof(uint4);   // 78.6 MB
    const size_t xs_bytes = (size_t)B_*4*N_*sizeof(uint4);   // 39.3 MB

    uint4* P0h   = (uint4*)d_ws;
    uint4* X1S1h = (uint4*)((char*)d_ws + p0_bytes);
    float* accum = (float*)((char*)d_ws + p0_bytes + xs_bytes);    // 3*B_*27 floats
    unsigned* counter = (unsigned*)(accum + 3*B_*27);

    hipLaunchKernelGGL(precompute_kernel, dim3(N_/256, 4, B_), dim3(256), 0, stream,
                       x0, x1, sigma0, sigma1, P0h, X1S1h, accum, counter);

    dim3 grid(N_/512, B_);
    for (int it = 0; it < 3; ++it) {
        hipLaunchKernelGGL(iter_kernel, grid, dim3(256), 0, stream,
                           P0h, X1S1h, invD0, invD1, Kmat, twist0, accum, counter, out,
                           it, (it == 2) ? 1 : 0);
    }
}

// Round 7
// 335.295 us; speedup vs baseline: 1.2521x; 1.0671x over previous
//
#include <hip/hip_runtime.h>
#include <hip/hip_fp16.h>

#define B_ 8
#define C_ 16
#define H_ 240
#define W_ 320
#define N_ (H_*W_)

__device__ __forceinline__ void twist2mat_dev(float w0, float w1, float w2, float R[9]) {
    float th = sqrtf(w0*w0 + w1*w1 + w2*w2) + 1e-12f;
    float ax = w0/th, ay = w1/th, az = w2/th;
    float s = sinf(th), c = cosf(th), ic = 1.0f - c;
    R[0] = 1.0f + ic*(ax*ax - 1.0f);
    R[1] = -s*az + ic*ax*ay;
    R[2] =  s*ay + ic*ax*az;
    R[3] =  s*az + ic*ax*ay;
    R[4] = 1.0f + ic*(ay*ay - 1.0f);
    R[5] = -s*ax + ic*ay*az;
    R[6] = -s*ay + ic*ax*az;
    R[7] =  s*ax + ic*ay*az;
    R[8] = 1.0f + ic*(az*az - 1.0f);
}

__device__ __forceinline__ unsigned pack_h2(float a, float b) {
    __half2 h = __floats2half2_rn(a, b);
    return *reinterpret_cast<unsigned*>(&h);
}
__device__ __forceinline__ float2 unpack_h2(unsigned u) {
    __half2 h = *reinterpret_cast<__half2*>(&u);
    return __half22float2(h);
}

// One damped-GN solve step from accumulated [21 upper-tri JtWJ | 6 rhs]; updates R,t.
__device__ __forceinline__ void solve_update(const float* __restrict__ ac, float R[9], float t[3]) {
    float M[6][7];
    {
        int idx = 0;
        #pragma unroll
        for (int k = 0; k < 6; k++)
            #pragma unroll
            for (int l = k; l < 6; l++) { M[k][l] = ac[idx]; M[l][k] = ac[idx]; idx++; }
    }
    const float trace = M[0][0]+M[1][1]+M[2][2]+M[3][3]+M[4][4]+M[5][5];
    const float lam = trace * 1e-6f;
    #pragma unroll
    for (int i = 0; i < 6; i++) { M[i][i] += lam; M[i][6] = ac[21+i]; }

    #pragma unroll
    for (int k = 0; k < 6; k++) {
        const float inv = 1.0f / M[k][k];
        #pragma unroll
        for (int i = k+1; i < 6; i++) {
            const float f = M[i][k] * inv;
            #pragma unroll
            for (int j = k; j < 7; j++) M[i][j] -= f * M[k][j];
        }
    }
    float xi[6];
    #pragma unroll
    for (int i = 5; i >= 0; i--) {
        float s = M[i][6];
        #pragma unroll
        for (int j = i+1; j < 6; j++) s -= M[i][j]*xi[j];
        xi[i] = s / M[i][i];
    }

    float dR[9];
    twist2mat_dev(-xi[0], -xi[1], -xi[2], dR);
    const float dt0 = -(dR[0]*xi[3] + dR[1]*xi[4] + dR[2]*xi[5]);
    const float dt1 = -(dR[3]*xi[3] + dR[4]*xi[4] + dR[5]*xi[5]);
    const float dt2 = -(dR[6]*xi[3] + dR[7]*xi[4] + dR[8]*xi[5]);

    const float nt0 = R[0]*dt0 + R[1]*dt1 + R[2]*dt2 + t[0];
    const float nt1 = R[3]*dt0 + R[4]*dt1 + R[5]*dt2 + t[1];
    const float nt2 = R[6]*dt0 + R[7]*dt1 + R[8]*dt2 + t[2];
    float nR[9];
    #pragma unroll
    for (int i = 0; i < 3; i++)
        #pragma unroll
        for (int j = 0; j < 3; j++)
            nR[i*3+j] = R[i*3+0]*dR[0*3+j] + R[i*3+1]*dR[1*3+j] + R[i*3+2]*dR[2*3+j];
    #pragma unroll
    for (int i = 0; i < 9; i++) R[i] = nR[i];
    t[0] = nt0; t[1] = nt1; t[2] = nt2;
}

__device__ __forceinline__ void build_RT(const float* __restrict__ twist0,
                                         const float* __restrict__ accum,
                                         int b, int iters, float R[9], float t[3]) {
    const float* w = twist0 + b*6;
    twist2mat_dev(w[0], w[1], w[2], R);
    t[0] = w[3]; t[1] = w[4]; t[2] = w[5];
    for (int j = 0; j < iters; j++)
        solve_update(accum + (size_t)(j*B_ + b)*27, R, t);
}

// Iteration-invariant precompute, 1 pixel x 4 channels per thread.
// ALL global reads are cooperative float4 through LDS: x0 sobel tile (20 KB)
// plus x1/sigma0/sigma1 aux (12 KB). VMEM instr/thread: 20 -> 11
// (precompute measured VMEM-issue-bound at ~1 instr/cyc/CU).
//  P0h  : [b][cp=0..7][pix] uint4 = {h2(gx,gy), h2(x0,s0^2)} x 2 channels (16 B)
//  X1S1h: [b][cg=0..3][pix] uint4 = h2(x1,s1) x 4 channels (16 B, gather target)
// Block (0,0,0) also zeroes the 3 per-iteration accumulator sets.
__launch_bounds__(256)
__global__ void precompute_kernel(const float* __restrict__ x0, const float* __restrict__ x1,
                                  const float* __restrict__ sigma0, const float* __restrict__ sigma1,
                                  uint4* __restrict__ P0h, uint4* __restrict__ X1S1h,
                                  float* __restrict__ accum)
{
    if (blockIdx.x == 0 && blockIdx.y == 0 && blockIdx.z == 0) {
        for (int k = threadIdx.x; k < 3*B_*27; k += 256) accum[k] = 0.0f;
    }
    const int b  = blockIdx.z;
    const int cg = blockIdx.y;
    const int base_pix = blockIdx.x * 256;
    const int pix = base_pix + threadIdx.x;
    const int h0 = base_pix / W_;          // first row touched by this block

    __shared__ float lds[4][4][W_];        // x0 [ch][row][col], 20 KB
    __shared__ float auxl[3][4][256];      // {x1,s0,s1}[ch][px], 12 KB

    const size_t cbase = ((size_t)(b*C_) + cg*4) * N_;

    // cooperative x0 tile: 4 ch x 4 rows (h0-1..h0+2, clamped) x 320 cols
    // = 1280 float4 loads for the block -> 5 per thread, fully coalesced.
    #pragma unroll
    for (int k = 0; k < 5; k++) {
        const int idx = threadIdx.x + k*256;          // 0..1279
        const int ch  = idx / 320;
        const int rem = idx - ch*320;
        const int row = rem / 80;
        const int c4  = rem - row*80;
        const int src_r = min(max(h0 - 1 + row, 0), H_ - 1);
        const float4 v = *reinterpret_cast<const float4*>(
            x0 + cbase + (size_t)ch*N_ + (size_t)src_r*W_ + c4*4);
        *reinterpret_cast<float4*>(&lds[ch][row][c4*4]) = v;
    }
    // cooperative aux: per array, wave w loads channel w's 256 px as 64 float4
    {
        const int ch = threadIdx.x >> 6;              // 0..3 (one wave per channel)
        const int c4 = threadIdx.x & 63;              // 0..63
        const size_t off = cbase + (size_t)ch*N_ + base_pix + c4*4;
        const float4 v0 = *reinterpret_cast<const float4*>(x1     + off);
        const float4 v1 = *reinterpret_cast<const float4*>(sigma0 + off);
        const float4 v2 = *reinterpret_cast<const float4*>(sigma1 + off);
        *reinterpret_cast<float4*>(&auxl[0][ch][c4*4]) = v0;
        *reinterpret_cast<float4*>(&auxl[1][ch][c4*4]) = v1;
        *reinterpret_cast<float4*>(&auxl[2][ch][c4*4]) = v2;
    }
    __syncthreads();

    const int h = pix / W_;
    const int w = pix - h*W_;
    const int lr = h - (h0 - 1);                      // 1 or 2
    const int wm = max(w-1, 0), wp = min(w+1, W_-1);

    unsigned gq[4], xq[4], qq[4];
    #pragma unroll
    for (int i = 0; i < 4; i++) {
        const float* rT = lds[i][lr-1];
        const float* rM = lds[i][lr];
        const float* rB = lds[i][lr+1];
        const float tl = rT[wm], tc_ = rT[w], tr = rT[wp];
        const float ml = rM[wm], ctr = rM[w], mr = rM[wp];
        const float bl = rB[wm], bc_ = rB[w], br = rB[wp];
        const float dx = tr - tl + 2.0f*(mr - ml) + (br - bl);
        const float dy = bl - tl + 2.0f*(bc_ - tc_) + (br - tr);
        const float mag = sqrtf(dx*dx + dy*dy + 1e-8f);
        const float s0v = auxl[1][i][threadIdx.x];
        gq[i] = pack_h2(dx/mag, dy/mag);
        xq[i] = pack_h2(ctr, s0v*s0v);
        qq[i] = pack_h2(auxl[0][i][threadIdx.x], auxl[2][i][threadIdx.x]);
    }

    uint4 A;  A.x = gq[0];  A.y = xq[0];  A.z = gq[1];  A.w = xq[1];
    uint4 Bw; Bw.x = gq[2]; Bw.y = xq[2]; Bw.z = gq[3]; Bw.w = xq[3];
    uint4 Q;  Q.x = qq[0];  Q.y = qq[1];  Q.z = qq[2];  Q.w = qq[3];
    P0h[((size_t)(b*8 + cg*2  ))*N_ + pix] = A;
    P0h[((size_t)(b*8 + cg*2+1))*N_ + pix] = Bw;
    X1S1h[((size_t)(b*4 + cg))*N_ + pix] = Q;
}

// Per-pixel residual/weight accumulation into the shared 27-value accumulator.
// (Round-2 verified body, unchanged.)
__device__ __forceinline__ void accum_pixel(int pix,
                                            const float Rm[9], const float tv[3],
                                            float fx, float fy, float cx, float cy,
                                            const uint4* __restrict__ P0b,
                                            const uint4* __restrict__ X1S1b,
                                            const float* __restrict__ d0,
                                            const float* __restrict__ dz,
                                            float* __restrict__ acc)
{
    const int h = pix / W_;
    const int w = pix - h*W_;

    const float px = ((float)w - cx) / fx;
    const float py = ((float)h - cy) / fy;
    const float d  = d0[pix];

    const float x_ = Rm[0]*px + Rm[1]*py + Rm[2] + tv[0]*d;
    const float y_ = Rm[3]*px + Rm[4]*py + Rm[5] + tv[1]*d;
    const float s_ = Rm[6]*px + Rm[7]*py + Rm[8] + tv[2]*d;
    const float u = x_/s_*fx + cx;
    const float v = y_/s_*fy + cy;
    const float inv_z = d / s_;

    const float uc = fminf(fmaxf(u, 0.0f), (float)(W_-1));
    const float vc = fminf(fmaxf(v, 0.0f), (float)(H_-1));
    const float x0f = floorf(uc), y0f = floorf(vc);
    const float wx = uc - x0f, wy = vc - y0f;
    const int x0i = (int)x0f, y0i = (int)y0f;
    const int x1i = min(x0i+1, W_-1), y1i = min(y0i+1, H_-1);
    const float w00 = (1.0f-wx)*(1.0f-wy), w01 = wx*(1.0f-wy);
    const float w10 = (1.0f-wx)*wy,        w11 = wx*wy;
    const int i00 = y0i*W_+x0i, i01 = y0i*W_+x1i, i10 = y1i*W_+x0i, i11 = y1i*W_+x1i;

    const float zw = dz[i00]*w00 + dz[i01]*w01 + dz[i10]*w10 + dz[i11]*w11;
    const bool inlier = inv_z > zw - 0.1f;
    const bool inview = (u > 0.0f) && (u < (float)W_) && (v > 0.0f) && (v < (float)H_);
    const bool valid  = inlier && inview;

    if (!valid) return;

    const float xy = px*py;
    const float Av[6] = { -xy*fx, (1.0f+px*px)*fx, -py*fx, d*fx, 0.0f, -d*px*fx };
    const float Bv[6] = { -(1.0f+py*py)*fy, xy*fy, px*fy, 0.0f, d*fy, -d*py*fy };

    float Swxx=0.f, Swxy=0.f, Swyy=0.f, Srx=0.f, Sry=0.f;

#define CH(gword, xword, t00, t01, t10, t11) { \
    const float2 g  = unpack_h2(gword); \
    const float2 xs = unpack_h2(xword); \
    const float2 a00 = unpack_h2(t00), a01 = unpack_h2(t01), \
                 a10 = unpack_h2(t10), a11 = unpack_h2(t11); \
    const float fr = a00.x*w00 + a01.x*w01 + a10.x*w10 + a11.x*w11; \
    const float sr = a00.y*w00 + a01.y*w01 + a10.y*w10 + a11.y*w11; \
    const float inv_s2 = 1.0f/(sr*sr + xs.y); \
    const float res = fr - xs.x; \
    const float gxw = g.x*inv_s2, gyw = g.y*inv_s2; \
    Swxx += g.x*gxw; Swxy += g.x*gyw; Swyy += g.y*gyw; \
    Srx  += res*gxw; Sry  += res*gyw; }

    #pragma unroll
    for (int cgi = 0; cgi < 4; cgi++) {
        const uint4 pA = P0b[(size_t)(cgi*2  )*N_ + pix];
        const uint4 pB = P0b[(size_t)(cgi*2+1)*N_ + pix];
        const uint4* xsb = X1S1b + (size_t)cgi*N_;
        const uint4 q00 = xsb[i00], q01 = xsb[i01], q10 = xsb[i10], q11 = xsb[i11];
        CH(pA.x, pA.y, q00.x, q01.x, q10.x, q11.x)
        CH(pA.z, pA.w, q00.y, q01.y, q10.y, q11.y)
        CH(pB.x, pB.y, q00.z, q01.z, q10.z, q11.z)
        CH(pB.z, pB.w, q00.w, q01.w, q10.w, q11.w)
    }
#undef CH

    int idx = 0;
    #pragma unroll
    for (int k = 0; k < 6; k++) {
        #pragma unroll
        for (int l = k; l < 6; l++) {
            acc[idx++] += Swxx*Av[k]*Av[l] + Swxy*(Av[k]*Bv[l] + Bv[k]*Av[l]) + Swyy*Bv[k]*Bv[l];
        }
    }
    #pragma unroll
    for (int k = 0; k < 6; k++) acc[21+k] += Srx*Av[k] + Sry*Bv[k];
}

// 2 pixels per thread (R2 verified structure, byte-exact: no finalize tail,
// no extra args -> keeps VGPR/SGPR pressure at the measured-good level).
__launch_bounds__(256)
__global__ void iter_kernel(const uint4* __restrict__ P0h, const uint4* __restrict__ X1S1h,
                            const float* __restrict__ invD0, const float* __restrict__ invD1,
                            const float* __restrict__ Kmat, const float* __restrict__ twist0,
                            float* __restrict__ accum, int it)
{
    const int b = blockIdx.y;
    const int pix0 = blockIdx.x * 512 + threadIdx.x;

    float Rm[9], tv[3];
    build_RT(twist0, accum, b, it, Rm, tv);

    const float fx = Kmat[b*4+0], fy = Kmat[b*4+1], cx = Kmat[b*4+2], cy = Kmat[b*4+3];

    float acc[27];
    #pragma unroll
    for (int j = 0; j < 27; j++) acc[j] = 0.0f;

    const uint4* P0b   = P0h   + (size_t)b*8*N_;
    const uint4* X1S1b = X1S1h + (size_t)b*4*N_;
    const float* d0 = invD0 + b*N_;
    const float* dz = invD1 + b*N_;

    accum_pixel(pix0,       Rm, tv, fx, fy, cx, cy, P0b, X1S1b, d0, dz, acc);
    accum_pixel(pix0 + 256, Rm, tv, fx, fy, cx, cy, P0b, X1S1b, d0, dz, acc);

    const int lane = threadIdx.x & 63;
    const int wave = threadIdx.x >> 6;
    __shared__ float red[4][27];
    #pragma unroll
    for (int j = 0; j < 27; j++) {
        float vv = acc[j];
        vv += __shfl_down(vv, 32);
        vv += __shfl_down(vv, 16);
        vv += __shfl_down(vv, 8);
        vv += __shfl_down(vv, 4);
        vv += __shfl_down(vv, 2);
        vv += __shfl_down(vv, 1);
        if (lane == 0) red[wave][j] = vv;
    }
    __syncthreads();
    if (threadIdx.x < 27) {
        float s = red[0][threadIdx.x] + red[1][threadIdx.x] + red[2][threadIdx.x] + red[3][threadIdx.x];
        atomicAdd(&accum[(size_t)(it*B_ + b)*27 + threadIdx.x], s);
    }
}

__global__ void finalize_kernel(const float* __restrict__ twist0, const float* __restrict__ accum,
                                float* __restrict__ out)
{
    const int b = threadIdx.x;
    if (b >= B_) return;
    float Rm[9], tv[3];
    build_RT(twist0, accum, b, 3, Rm, tv);
    float* ob = out + b*12;
    #pragma unroll
    for (int i = 0; i < 9; i++) ob[i] = Rm[i];
    ob[9] = tv[0]; ob[10] = tv[1]; ob[11] = tv[2];
}

extern "C" void kernel_launch(void* const* d_in, const int* in_sizes, int n_in,
                              void* d_out, int out_size, void* d_ws, size_t ws_size,
                              hipStream_t stream) {
    const float* twist0 = (const float*)d_in[0];
    const float* x0     = (const float*)d_in[1];
    const float* x1     = (const float*)d_in[2];
    const float* invD0  = (const float*)d_in[3];
    const float* invD1  = (const float*)d_in[4];
    const float* sigma0 = (const float*)d_in[5];
    const float* sigma1 = (const float*)d_in[6];
    const float* Kmat   = (const float*)d_in[7];
    float* out = (float*)d_out;

    const size_t p0_bytes = (size_t)B_*8*N_*sizeof(uint4);   // 78.6 MB
    const size_t xs_bytes = (size_t)B_*4*N_*sizeof(uint4);   // 39.3 MB

    uint4* P0h   = (uint4*)d_ws;
    uint4* X1S1h = (uint4*)((char*)d_ws + p0_bytes);
    float* accum = (float*)((char*)d_ws + p0_bytes + xs_bytes);  // 3*B_*27 floats

    hipLaunchKernelGGL(precompute_kernel, dim3(N_/256, 4, B_), dim3(256), 0, stream,
                       x0, x1, sigma0, sigma1, P0h, X1S1h, accum);

    dim3 grid(N_/512, B_);
    for (int it = 0; it < 3; ++it) {
        hipLaunchKernelGGL(iter_kernel, grid, dim3(256), 0, stream,
                           P0h, X1S1h, invD0, invD1, Kmat, twist0, accum, it);
    }
    hipLaunchKernelGGL(finalize_kernel, dim3(1), dim3(64), 0, stream, twist0, accum, out);
}